// Round 6
// baseline (173.787 us; speedup 1.0000x reference)
//
#include <hip/hip_runtime.h>
#include <stdint.h>
#include <math.h>

// Problem constants (from reference: B=2048, D=512, TAU=0.5)
#define DIM       512
#define NROWS     8192      // 4*B
#define HALF_ROWS 4096      // 2*B
#define TILE      128
#define BK        64
#define NT        64        // 8192/128 tiles per side
#define NTRI      2080      // NT*(NT+1)/2 upper-triangle tiles
#define CPX       260       // tiles per XCD chunk (2080/8, exact)

typedef float  floatx4 __attribute__((ext_vector_type(4)));
typedef __bf16 bf16x8  __attribute__((ext_vector_type(8)));

__device__ __forceinline__ void async_copy16(const unsigned short* g, unsigned short* l) {
    __builtin_amdgcn_global_load_lds(
        (const __attribute__((address_space(1))) uint32_t*)(g),
        (__attribute__((address_space(3))) uint32_t*)(l),
        16, 0, 0);
}

// L2-normalize rows of [emb_i; emb_j] -> bf16 rep[8192][512]; also zero ws.
__global__ __launch_bounds__(256) void normalize_kernel(
    const float* __restrict__ emb_i, const float* __restrict__ emb_j,
    unsigned short* __restrict__ rep, double* __restrict__ ws)
{
    if (blockIdx.x == 0 && threadIdx.x == 0) {
        ws[0] = 0.0; ws[1] = 0.0;
        ((unsigned long long*)ws)[2] = 0ull;   // completion counter
    }
    const int wave = threadIdx.x >> 6;
    const int lane = threadIdx.x & 63;
    const int row  = blockIdx.x * 4 + wave;
    const float* src = (row < HALF_ROWS) ? (emb_i + (size_t)row * DIM)
                                         : (emb_j + (size_t)(row - HALF_ROWS) * DIM);
    const int c = lane * 8;
    float4 v0 = *(const float4*)(src + c);
    float4 v1 = *(const float4*)(src + c + 4);
    float s = v0.x*v0.x + v0.y*v0.y + v0.z*v0.z + v0.w*v0.w
            + v1.x*v1.x + v1.y*v1.y + v1.z*v1.z + v1.w*v1.w;
    #pragma unroll
    for (int off = 32; off; off >>= 1) s += __shfl_xor(s, off, 64);
    const float inv = 1.0f / fmaxf(sqrtf(s), 1e-12f);
    float f[8] = {v0.x*inv, v0.y*inv, v0.z*inv, v0.w*inv,
                  v1.x*inv, v1.y*inv, v1.z*inv, v1.w*inv};
    union { unsigned short h[8]; uint4 u; } pk;
    #pragma unroll
    for (int t = 0; t < 8; ++t) {   // fp32 -> bf16 RNE
        uint32_t b = __float_as_uint(f[t]);
        b += 0x7FFFu + ((b >> 16) & 1u);
        pk.h[t] = (unsigned short)(b >> 16);
    }
    *(uint4*)(rep + (size_t)row * DIM + c) = pk.u;
}

// Stage one K-tile: A rows [i0,i0+128) and B rows [j0,j0+128), 64 cols each,
// into LDS (linear dest; bank swizzle byte^=(row&7)<<4 applied by permuting
// the GLOBAL source slot — both-sides-or-neither, XOR is its own inverse).
// 8 x 16B loads per thread (4 A + 4 B).
__device__ __forceinline__ void stage_tile(const unsigned short* __restrict__ rep,
    int i0, int j0, int k0, unsigned short* A, unsigned short* Bb, int tid)
{
    #pragma unroll
    for (int l = 0; l < 4; ++l) {
        const int ch  = l * 256 + tid;          // 1024 chunks of 16 B each side
        const int row = ch >> 3;                // 8 chunks per 64-col row
        const int s   = ch & 7;
        const int col = (s ^ (row & 7)) << 3;   // pre-swizzled source slot
        async_copy16(rep + (size_t)(i0 + row) * DIM + k0 + col, A  + ch * 8);
        async_copy16(rep + (size_t)(j0 + row) * DIM + k0 + col, Bb + ch * 8);
    }
}

#define WAIT_VM0() asm volatile("s_waitcnt vmcnt(0)" ::: "memory")

// ds_read both operand fragment sets from buffer CUR, then 32 MFMA.
#define COMPUTE_TILE(CUR) do { \
    bf16x8 af[4][2], bf[4][2]; \
    _Pragma("unroll") \
    for (int mt = 0; mt < 4; ++mt) { \
        const char* rp = (const char*)(sA[CUR]) + (size_t)(wm * 64 + mt * 16 + m) * 128; \
        af[mt][0] = *(const bf16x8*)(rp + ((quad * 16) ^ swz)); \
        af[mt][1] = *(const bf16x8*)(rp + ((64 + quad * 16) ^ swz)); \
    } \
    _Pragma("unroll") \
    for (int nt = 0; nt < 4; ++nt) { \
        const char* rp = (const char*)(sB[CUR]) + (size_t)(wn * 64 + nt * 16 + m) * 128; \
        bf[nt][0] = *(const bf16x8*)(rp + ((quad * 16) ^ swz)); \
        bf[nt][1] = *(const bf16x8*)(rp + ((64 + quad * 16) ^ swz)); \
    } \
    asm volatile("s_waitcnt lgkmcnt(0)" ::: "memory"); \
    __builtin_amdgcn_sched_barrier(0); \
    __builtin_amdgcn_s_setprio(1); \
    _Pragma("unroll") \
    for (int mt = 0; mt < 4; ++mt) \
        _Pragma("unroll") \
        for (int nt = 0; nt < 4; ++nt) \
            _Pragma("unroll") \
            for (int ks = 0; ks < 2; ++ks) \
                acc[mt][nt] = __builtin_amdgcn_mfma_f32_16x16x32_bf16( \
                    af[mt][ks], bf[nt][ks], acc[mt][nt], 0, 0, 0); \
    __builtin_amdgcn_s_setprio(0); \
} while (0)

// 2-phase double-buffered 128x128 Gram tile + fused exp/band reduction.
// 4 waves (2x2 quadrants of 64x64); BK=64; 16x16x32 MFMA (conflict-free
// swizzled reads — R1 measured 0 SQ_LDS_BANK_CONFLICT with this pattern).
// LDS 64 KB -> 2 independent blocks/CU (desynchronized stall overlap).
__global__ __launch_bounds__(256) void gram_kernel(
    const unsigned short* __restrict__ rep, double* __restrict__ ws,
    float* __restrict__ out)
{
    __shared__ unsigned short sA[2][TILE * BK];   // 2 x 16 KB
    __shared__ unsigned short sB[2][TILE * BK];   // 2 x 16 KB
    __shared__ float red[8];

    const int tid  = threadIdx.x;
    const int wave = tid >> 6, lane = tid & 63;
    const int wm = wave >> 1, wn = wave & 1;      // 2x2 waves of 64x64 quadrants
    const int m = lane & 15, quad = lane >> 4;    // MFMA fragment coords
    const int swz = (m & 7) << 4;                 // matches staging swizzle

    // XCD-chunked triangle walk: blk%8 -> XCD (HW round-robin), each XCD gets
    // 260 consecutive triangle tiles.
    const int u = (blockIdx.x & 7) * CPX + (blockIdx.x >> 3);
    int bi = (int)((2.0f * NT + 1.0f
             - sqrtf((2.0f * NT + 1.0f) * (2.0f * NT + 1.0f) - 8.0f * (float)u)) * 0.5f);
    while ((bi + 1) * NT - ((bi + 1) * bi) / 2 <= u) ++bi;
    while (bi * NT - (bi * (bi - 1)) / 2 > u) --bi;
    const int bj = bi + (u - (bi * NT - (bi * (bi - 1)) / 2));
    const int i0 = bi * TILE, j0 = bj * TILE;

    floatx4 acc[4][4];
    #pragma unroll
    for (int a = 0; a < 4; ++a)
        #pragma unroll
        for (int b = 0; b < 4; ++b)
            #pragma unroll
            for (int e = 0; e < 4; ++e) acc[a][b][e] = 0.0f;

    // Prologue: stage K-tile 0 into buf0, drain, barrier.
    stage_tile(rep, i0, j0, 0, sA[0], sB[0], tid);
    WAIT_VM0();
    __builtin_amdgcn_s_barrier();
    __builtin_amdgcn_sched_barrier(0);

    // Steady state (rolled, 7 iters): issue STAGE(next) first, then
    // ds_read(cur)+MFMA overlap the staging flight; one vmcnt(0)+barrier
    // per K-iter, drained only after MFMA (T3-minimum recipe).
    int cur = 0;
    for (int t = 0; t < 7; ++t) {
        stage_tile(rep, i0, j0, (t + 1) * BK, sA[cur ^ 1], sB[cur ^ 1], tid);
        COMPUTE_TILE(cur);
        WAIT_VM0();                       // next tile landed (hidden under MFMA)
        __builtin_amdgcn_s_barrier();
        __builtin_amdgcn_sched_barrier(0);
        cur ^= 1;
    }
    COMPUTE_TILE(cur);                    // final K-tile: no prefetch

    // Epilogue: exp(sim/tau) = exp2(sim * 2/ln2); band + total sums.
    // 16x16 C/D layout: col = lane&15, row = (lane>>4)*4 + reg.
    float s_all = 0.0f, s_pos = 0.0f;
    const float LOG2E2 = 2.885390081777927f;  // 2 / ln(2)
    #pragma unroll
    for (int mt = 0; mt < 4; ++mt) {
        const int ibase = i0 + wm * 64 + mt * 16 + quad * 4;
        #pragma unroll
        for (int nt = 0; nt < 4; ++nt) {
            const int j = j0 + wn * 64 + nt * 16 + m;
            const floatx4 v = acc[mt][nt];
            #pragma unroll
            for (int r2 = 0; r2 < 4; ++r2) {
                const int i = ibase + r2;
                const float ex = exp2f(v[r2] * LOG2E2);
                if (i != j) s_all += ex;
                const int d = j - i;          // upper triangle: positive bands
                if (d == 2048 || d == 4096 || d == 6144) s_pos += ex;
            }
        }
    }
    #pragma unroll
    for (int off = 32; off; off >>= 1) {
        s_all += __shfl_xor(s_all, off, 64);
        s_pos += __shfl_xor(s_pos, off, 64);
    }
    if (lane == 0) { red[wave] = s_all; red[4 + wave] = s_pos; }
    __syncthreads();
    if (tid == 0) {
        const float wgt = (bi == bj) ? 1.0f : 2.0f;  // off-diag covers transpose
        const float ta = (red[0] + red[1] + red[2] + red[3]) * wgt;
        const float tp = (red[4] + red[5] + red[6] + red[7]) * wgt;
        atomicAdd(&ws[0], (double)ta);
        atomicAdd(&ws[1], (double)tp);
        __threadfence();
        unsigned* ctr = (unsigned*)(ws + 2);
        const unsigned done = atomicAdd(ctr, 1u);
        if (done == NTRI - 1) {               // last tile: fused finalize
            __threadfence();
            const double nom = atomicAdd(&ws[1], 0.0);
            const double den = atomicAdd(&ws[0], 0.0) - nom;
            out[0] = (float)(-log(nom / den) / (double)NROWS);
        }
    }
}

extern "C" void kernel_launch(void* const* d_in, const int* in_sizes, int n_in,
                              void* d_out, int out_size, void* d_ws, size_t ws_size,
                              hipStream_t stream) {
    const float* emb_i = (const float*)d_in[0];
    const float* emb_j = (const float*)d_in[1];
    float* out = (float*)d_out;
    double* ws = (double*)d_ws;                                   // accums + counter
    unsigned short* rep = (unsigned short*)((char*)d_ws + 256);   // bf16 [8192][512]

    hipLaunchKernelGGL(normalize_kernel, dim3(NROWS / 4), dim3(256), 0, stream,
                       emb_i, emb_j, rep, ws);
    hipLaunchKernelGGL(gram_kernel, dim3(NTRI), dim3(256), 0, stream, rep, ws, out);
}